// Round 1
// baseline (695.680 us; speedup 1.0000x reference)
//
#include <hip/hip_runtime.h>

// ---------------- problem constants ----------------
#define N_TOK 8192      // B*S tokens
#define H_DIM 1024
#define I_DIM 2048
#define N_EXP 8
#define TOPK  2
#define CAP   17408     // 16384 + 8*128 (per-expert padding to 128)
#define MT_MAX 136      // CAP / 128

// ---------------- workspace layout (bytes) ----------------
#define OFF_TOPK_I 0u          // 16384 i32
#define OFF_TOPK_W 65536u      // 16384 f32 (RAW softmax probs of chosen experts)
#define OFF_COUNTS 131072u     // 8 i32
#define OFF_LOAD   131104u     // 8 f32
#define OFF_CURSOR 131136u     // 8 i32
#define OFF_PO     131168u     // 16 i32
#define OFF_TILE_E 131232u     // 152 i32 (136 used)
#define OFF_BTOK   131840u     // 17408 i32
#define OFF_BW     201472u     // 17408 f32
#define CTRL_BYTES 271104u
#define OFF_WGT  1048576u                      // 8*2048*1024*2 = 33554432
#define OFF_WUT  (OFF_WGT + 33554432u)
#define OFF_WDT  (OFF_WUT + 33554432u)
#define OFF_HB   (OFF_WDT + 33554432u)         // 17408*2048*2 = 71303168
#define OFF_XB   (OFF_HB + 71303168u)          // 8192*1024*2 = 16777216 (x in bf16)

typedef __attribute__((ext_vector_type(8))) short bf16x8;
typedef __attribute__((ext_vector_type(8))) unsigned short u16x8;
typedef __attribute__((ext_vector_type(4))) float f32x4;

__device__ __forceinline__ unsigned short f2bf(float f) {
  union { float f; unsigned int u; } v; v.f = f;
  unsigned int r = (v.u + 0x7FFFu + ((v.u >> 16) & 1u)) >> 16;
  return (unsigned short)r;
}
__device__ __forceinline__ u16x8 pack8(float4 a, float4 b) {
  u16x8 r;
  r[0] = f2bf(a.x); r[1] = f2bf(a.y); r[2] = f2bf(a.z); r[3] = f2bf(a.w);
  r[4] = f2bf(b.x); r[5] = f2bf(b.y); r[6] = f2bf(b.z); r[7] = f2bf(b.w);
  return r;
}
__device__ __forceinline__ f32x4 mfma32(bf16x8 a, bf16x8 b, f32x4 c) {
  return __builtin_amdgcn_mfma_f32_16x16x32_bf16(a, b, c, 0, 0, 0);
}
// async global->LDS, 16B per lane; lds dest must be wave-uniform base (HW adds lane*16)
__device__ __forceinline__ void gll16(const void* g, void* l) {
  __builtin_amdgcn_global_load_lds(
      (const __attribute__((address_space(1))) unsigned int*)g,
      (__attribute__((address_space(3))) unsigned int*)l, 16, 0, 0);
}

// ---------------- K1: x f32 -> bf16 (once; GEMM1 A-operand becomes lds-DMA-able) ----------------
__global__ __launch_bounds__(256) void k_xcast(const float* __restrict__ x,
                                               unsigned short* __restrict__ xb)
{
  int idx = blockIdx.x * 256 + threadIdx.x;          // 8 floats each
  const float4* s = (const float4*)x + (size_t)idx * 2;
  float4 a = s[0], b = s[1];
  *(u16x8*)&xb[(size_t)idx * 8] = pack8(a, b);
}

// ---------------- K2: tiled transpose f32 -> bf16 of the 3 weight tensors ----------------
__global__ __launch_bounds__(256) void k_transpose(
    const float* __restrict__ wg, const float* __restrict__ wu, const float* __restrict__ wd,
    unsigned short* __restrict__ wgT, unsigned short* __restrict__ wuT,
    unsigned short* __restrict__ wdT)
{
  __shared__ unsigned short lds[64][65];
  int bid = blockIdx.x;
  int m = bid / 4096; int rem = bid % 4096;
  const float* src; unsigned short* dst; int R, C;
  if (m == 0)      { src = wg; dst = wgT; R = 1024; C = 2048; }
  else if (m == 1) { src = wu; dst = wuT; R = 1024; C = 2048; }
  else             { src = wd; dst = wdT; R = 2048; C = 1024; }
  int e = rem / 512; int trem = rem % 512;
  int tcc = C / 64;
  int r0 = (trem / tcc) * 64, c0 = (trem % tcc) * 64;
  size_t ebase = (size_t)e * R * C;
  dst += ebase;
  int tid = threadIdx.x;
  int lr = tid >> 3;            // 0..31
  int lc = (tid & 7) * 8;       // 0..56
#pragma unroll
  for (int p = 0; p < 2; ++p) {
    int row = p * 32 + lr;
    size_t off = ebase + (size_t)(r0 + row) * C + c0 + lc;
    float4 q0 = *(const float4*)&src[off];
    float4 q1 = *(const float4*)&src[off + 4];
    unsigned short tmp[8]; *(u16x8*)tmp = pack8(q0, q1);
#pragma unroll
    for (int j = 0; j < 8; ++j) lds[row][lc + j] = tmp[j];
  }
  __syncthreads();
#pragma unroll
  for (int p = 0; p < 2; ++p) {
    int drow = p * 32 + lr;     // local c index
    unsigned short tmp[8];
#pragma unroll
    for (int j = 0; j < 8; ++j) tmp[j] = lds[lc + j][drow];
    *(u16x8*)&dst[(size_t)(c0 + drow) * R + r0 + lc] = *(const u16x8*)tmp;
  }
}

// ---------------- K3: router (1 wave per token, NO global atomics) ----------------
__global__ __launch_bounds__(256) void k_router(
    const float* __restrict__ x, const float* __restrict__ gw,
    int* __restrict__ topk_i, float* __restrict__ topk_w)
{
  int wave = threadIdx.x >> 6, lane = threadIdx.x & 63;
  int t = blockIdx.x * 4 + wave;
  const float* xr = x + (size_t)t * H_DIM;
  float acc[8];
#pragma unroll
  for (int e = 0; e < 8; ++e) acc[e] = 0.f;
#pragma unroll
  for (int it = 0; it < H_DIM / 64; ++it) {
    int h = it * 64 + lane;
    float xv = xr[h];
    float4 g0 = *(const float4*)&gw[h * 8];
    float4 g1 = *(const float4*)&gw[h * 8 + 4];
    acc[0] += xv * g0.x; acc[1] += xv * g0.y; acc[2] += xv * g0.z; acc[3] += xv * g0.w;
    acc[4] += xv * g1.x; acc[5] += xv * g1.y; acc[6] += xv * g1.z; acc[7] += xv * g1.w;
  }
#pragma unroll
  for (int off = 32; off > 0; off >>= 1) {
#pragma unroll
    for (int e = 0; e < 8; ++e) acc[e] += __shfl_xor(acc[e], off);
  }
  if (lane == 0) {
    float m = acc[0];
#pragma unroll
    for (int e = 1; e < 8; ++e) m = fmaxf(m, acc[e]);
    float p[8], s = 0.f;
#pragma unroll
    for (int e = 0; e < 8; ++e) { p[e] = __expf(acc[e] - m); s += p[e]; }
    float inv = 1.f / s;
#pragma unroll
    for (int e = 0; e < 8; ++e) p[e] *= inv;
    int i1 = 0;
#pragma unroll
    for (int e = 1; e < 8; ++e) if (p[e] > p[i1]) i1 = e;   // strict > = lowest-index ties
    int i2 = (i1 == 0) ? 1 : 0;
#pragma unroll
    for (int e = 0; e < 8; ++e) if (e != i1 && p[e] > p[i2]) i2 = e;
    topk_i[t * 2]     = i1; topk_i[t * 2 + 1] = i2;
    topk_w[t * 2]     = p[i1]; topk_w[t * 2 + 1] = p[i2];   // RAW probs
  }
}

// ---------------- K3b: histogram (counts + load) via LDS, few global atomics ----------------
__global__ __launch_bounds__(256) void k_hist(
    const int* __restrict__ topk_i, const float* __restrict__ topk_w,
    int* __restrict__ counts, float* __restrict__ loadw)
{
  __shared__ int c[8]; __shared__ float l[8];
  int tid = threadIdx.x;
  if (tid < 8) { c[tid] = 0; l[tid] = 0.f; }
  __syncthreads();
  int base = blockIdx.x * 1024 + tid * 4;   // 16 blocks cover 16384 entries
#pragma unroll
  for (int j = 0; j < 4; ++j) {
    int e = topk_i[base + j];
    float w = topk_w[base + j];
    atomicAdd(&c[e], 1);
    atomicAdd(&l[e], w);
  }
  __syncthreads();
  if (tid < 8) { atomicAdd(&counts[tid], c[tid]); atomicAdd(&loadw[tid], l[tid]); }
}

// ---------------- K4: padded offsets + tile->expert map + aux loss ----------------
__global__ __launch_bounds__(256) void k_offsets(
    const int* __restrict__ counts, const float* __restrict__ loadw,
    int* __restrict__ po, int* __restrict__ tile_e, float* __restrict__ out)
{
  __shared__ int spo[9];
  if (threadIdx.x == 0) {
    int a = 0;
    for (int e = 0; e < 8; ++e) { spo[e] = a; po[e] = a; a += (counts[e] + 127) & ~127; }
    spo[8] = a; po[8] = a;
    float s = 0.f;
    for (int e = 0; e < 8; ++e) s += loadw[e] * (float)counts[e];
    out[(size_t)N_TOK * H_DIM] =
        s * ((float)N_EXP * 1e-3f) / ((float)N_TOK * (float)N_TOK * (float)TOPK);
  }
  __syncthreads();
  int mt = threadIdx.x;
  if (mt < MT_MAX) {
    int te = -1, beg = mt * 128;
    if (beg < spo[8]) {
      for (int e = 0; e < 8; ++e) if (beg >= spo[e] && beg < spo[e + 1]) te = e;
    }
    tile_e[mt] = te;
  }
}

// ---------------- K5: bucket fill — LDS local ranks, 8 global atomics/block ----------------
__global__ __launch_bounds__(256) void k_bucket(
    const int* __restrict__ topk_i, const float* __restrict__ topk_w,
    const int* __restrict__ po, int* __restrict__ cursor,
    int* __restrict__ btok, float* __restrict__ bw)
{
  __shared__ int c[8];
  __shared__ int basee[8];
  int tid = threadIdx.x;
  if (tid < 8) c[tid] = 0;
  __syncthreads();
  int base = blockIdx.x * 1024 + tid * 4;   // 16 blocks cover 16384 entries
  int e4[4], r4[4]; float w4[4];
#pragma unroll
  for (int j = 0; j < 4; ++j) {
    int idx = base + j;
    int e = topk_i[idx];
    e4[j] = e;
    r4[j] = atomicAdd(&c[e], 1);            // LDS atomic: local rank
    int t = idx >> 1;
    float p0 = topk_w[t * 2], p1 = topk_w[t * 2 + 1];
    w4[j] = topk_w[idx] / (p0 + p1);        // renormalized weight
  }
  __syncthreads();
  if (tid < 8) basee[tid] = po[tid] + atomicAdd(&cursor[tid], c[tid]);
  __syncthreads();
#pragma unroll
  for (int j = 0; j < 4; ++j) {
    int slot = basee[e4[j]] + r4[j];
    btok[slot] = (base + j) >> 1;
    bw[slot] = w4[j];
  }
}

// ---------------- K6: grouped GEMM1 (global_load_lds staging), gate+up+SiLU -> hbuf ----------------
__global__ __launch_bounds__(256, 2) void k_gemm1(
    const unsigned short* __restrict__ xb,
    const unsigned short* __restrict__ wgT, const unsigned short* __restrict__ wuT,
    const int* __restrict__ btok, const int* __restrict__ tile_e,
    unsigned short* __restrict__ hbuf)
{
  int mt = blockIdx.x, nt = blockIdx.y;
  int e = tile_e[mt];
  if (e < 0) return;
  __shared__ unsigned short As[128 * 32];
  __shared__ unsigned short Bg[128 * 32];
  __shared__ unsigned short Bu[128 * 32];
  int tid = threadIdx.x;
  int wave = tid >> 6, lane = tid & 63;
  int wm = wave >> 1, wn = wave & 1;
  int quad = lane >> 4, l16 = lane & 15;

  // staging geometry: per 1KB wave-chunk, lane -> row = base + (lane>>2), k-chunk = (lane&3)*8
  int srow = lane >> 2;            // 0..15
  int sko  = (lane & 3) * 8;      // elem offset in K
  int ar0 = wave * 16 + srow;      // rows 0..63
  int ar1 = 64 + wave * 16 + srow; // rows 64..127
  int t0 = btok[mt * 128 + ar0];   // pad slots are 0 (memset) -> safe
  int t1 = btok[mt * 128 + ar1];
  const unsigned short* ga0 = xb + (size_t)t0 * H_DIM + sko;
  const unsigned short* ga1 = xb + (size_t)t1 * H_DIM + sko;
  const unsigned short* bgb = wgT + ((size_t)e * I_DIM + nt * 128) * H_DIM;
  const unsigned short* bub = wuT + ((size_t)e * I_DIM + nt * 128) * H_DIM;
  const unsigned short* gg0 = bgb + (size_t)ar0 * H_DIM + sko;
  const unsigned short* gg1 = bgb + (size_t)ar1 * H_DIM + sko;
  const unsigned short* gu0 = bub + (size_t)ar0 * H_DIM + sko;
  const unsigned short* gu1 = bub + (size_t)ar1 * H_DIM + sko;
  unsigned lb0 = (unsigned)(wave * 16) * 32;        // wave-uniform LDS elem base
  unsigned lb1 = (unsigned)(64 + wave * 16) * 32;

  f32x4 accG[4][4], accU[4][4];
  f32x4 z = {0.f, 0.f, 0.f, 0.f};
#pragma unroll
  for (int i = 0; i < 4; ++i)
#pragma unroll
    for (int j = 0; j < 4; ++j) { accG[i][j] = z; accU[i][j] = z; }

  for (int k0 = 0; k0 < H_DIM; k0 += 32) {
    gll16(ga0 + k0, &As[lb0]);
    gll16(ga1 + k0, &As[lb1]);
    gll16(gg0 + k0, &Bg[lb0]);
    gll16(gg1 + k0, &Bg[lb1]);
    gll16(gu0 + k0, &Bu[lb0]);
    gll16(gu1 + k0, &Bu[lb1]);
    __syncthreads();                                 // drains vmcnt -> LDS tiles ready
    bf16x8 af[4];
#pragma unroll
    for (int i = 0; i < 4; ++i)
      af[i] = *(const bf16x8*)&As[(wm * 64 + i * 16 + l16) * 32 + quad * 8];
#pragma unroll
    for (int j = 0; j < 4; ++j) {
      bf16x8 vg = *(const bf16x8*)&Bg[(wn * 64 + j * 16 + l16) * 32 + quad * 8];
      bf16x8 vu = *(const bf16x8*)&Bu[(wn * 64 + j * 16 + l16) * 32 + quad * 8];
#pragma unroll
      for (int i = 0; i < 4; ++i) {
        accG[i][j] = mfma32(af[i], vg, accG[i][j]);
        accU[i][j] = mfma32(af[i], vu, accU[i][j]);
      }
    }
    __syncthreads();
  }
#pragma unroll
  for (int i = 0; i < 4; ++i) {
#pragma unroll
    for (int r = 0; r < 4; ++r) {
      int row = mt * 128 + wm * 64 + i * 16 + quad * 4 + r;
      size_t base = (size_t)row * I_DIM + nt * 128 + wn * 64 + l16;
#pragma unroll
      for (int j = 0; j < 4; ++j) {
        float g = accG[i][j][r], u = accU[i][j][r];
        float sg = g / (1.f + __expf(-g));    // SiLU
        hbuf[base + j * 16] = f2bf(sg * u);
      }
    }
  }
}

// ---------------- K7: grouped GEMM2 (global_load_lds staging), scatter w*val into out ----------------
__global__ __launch_bounds__(256, 2) void k_gemm2(
    const unsigned short* __restrict__ hbuf, const unsigned short* __restrict__ wdT,
    const int* __restrict__ btok, const float* __restrict__ bw,
    const int* __restrict__ tile_e, float* __restrict__ yout)
{
  int mt = blockIdx.x, nt = blockIdx.y;
  int e = tile_e[mt];
  if (e < 0) return;
  __shared__ unsigned short As[128 * 32];
  __shared__ unsigned short Bs[128 * 32];
  int tid = threadIdx.x;
  int wave = tid >> 6, lane = tid & 63;
  int wm = wave >> 1, wn = wave & 1;
  int quad = lane >> 4, l16 = lane & 15;

  int srow = lane >> 2;
  int sko  = (lane & 3) * 8;
  int ar0 = wave * 16 + srow;
  int ar1 = 64 + wave * 16 + srow;
  const unsigned short* ga0 = hbuf + (size_t)(mt * 128 + ar0) * I_DIM + sko;
  const unsigned short* ga1 = hbuf + (size_t)(mt * 128 + ar1) * I_DIM + sko;
  const unsigned short* bb = wdT + ((size_t)e * H_DIM + nt * 128) * I_DIM;
  const unsigned short* gb0 = bb + (size_t)ar0 * I_DIM + sko;
  const unsigned short* gb1 = bb + (size_t)ar1 * I_DIM + sko;
  unsigned lb0 = (unsigned)(wave * 16) * 32;
  unsigned lb1 = (unsigned)(64 + wave * 16) * 32;

  f32x4 acc[4][4];
  f32x4 z = {0.f, 0.f, 0.f, 0.f};
#pragma unroll
  for (int i = 0; i < 4; ++i)
#pragma unroll
    for (int j = 0; j < 4; ++j) acc[i][j] = z;

  for (int k0 = 0; k0 < I_DIM; k0 += 32) {
    gll16(ga0 + k0, &As[lb0]);
    gll16(ga1 + k0, &As[lb1]);
    gll16(gb0 + k0, &Bs[lb0]);
    gll16(gb1 + k0, &Bs[lb1]);
    __syncthreads();
    bf16x8 af[4];
#pragma unroll
    for (int i = 0; i < 4; ++i)
      af[i] = *(const bf16x8*)&As[(wm * 64 + i * 16 + l16) * 32 + quad * 8];
#pragma unroll
    for (int j = 0; j < 4; ++j) {
      bf16x8 vb = *(const bf16x8*)&Bs[(wn * 64 + j * 16 + l16) * 32 + quad * 8];
#pragma unroll
      for (int i = 0; i < 4; ++i) acc[i][j] = mfma32(af[i], vb, acc[i][j]);
    }
    __syncthreads();
  }
#pragma unroll
  for (int i = 0; i < 4; ++i) {
#pragma unroll
    for (int r = 0; r < 4; ++r) {
      int s = mt * 128 + wm * 64 + i * 16 + quad * 4 + r;
      int t = btok[s];
      float w = bw[s];                          // 0 for pad slots (memset)
      int colb = nt * 128 + wn * 64 + l16;
#pragma unroll
      for (int j = 0; j < 4; ++j)
        atomicAdd(&yout[(size_t)t * H_DIM + colb + j * 16], w * acc[i][j][r]);
    }
  }
}

extern "C" void kernel_launch(void* const* d_in, const int* in_sizes, int n_in,
                              void* d_out, int out_size, void* d_ws, size_t ws_size,
                              hipStream_t stream)
{
  (void)in_sizes; (void)n_in; (void)out_size; (void)ws_size;
  const float* x  = (const float*)d_in[0];
  const float* gw = (const float*)d_in[1];
  const float* wg = (const float*)d_in[2];
  const float* wu = (const float*)d_in[3];
  const float* wd = (const float*)d_in[4];
  char* ws = (char*)d_ws;

  int*   topk_i = (int*)  (ws + OFF_TOPK_I);
  float* topk_w = (float*)(ws + OFF_TOPK_W);
  int*   counts = (int*)  (ws + OFF_COUNTS);
  float* loadw  = (float*)(ws + OFF_LOAD);
  int*   cursor = (int*)  (ws + OFF_CURSOR);
  int*   po     = (int*)  (ws + OFF_PO);
  int*   tile_e = (int*)  (ws + OFF_TILE_E);
  int*   btok   = (int*)  (ws + OFF_BTOK);
  float* bw     = (float*)(ws + OFF_BW);
  unsigned short* wgT  = (unsigned short*)(ws + OFF_WGT);
  unsigned short* wuT  = (unsigned short*)(ws + OFF_WUT);
  unsigned short* wdT  = (unsigned short*)(ws + OFF_WDT);
  unsigned short* hbuf = (unsigned short*)(ws + OFF_HB);
  unsigned short* xb   = (unsigned short*)(ws + OFF_XB);
  float* yout = (float*)d_out;

  (void)hipMemsetAsync(ws, 0, CTRL_BYTES, stream);
  (void)hipMemsetAsync(yout, 0, (size_t)N_TOK * H_DIM * sizeof(float), stream);
  k_xcast<<<(N_TOK * H_DIM) / 2048, 256, 0, stream>>>(x, xb);
  k_transpose<<<12288, 256, 0, stream>>>(wg, wu, wd, wgT, wuT, wdT);
  k_router<<<N_TOK / 4, 256, 0, stream>>>(x, gw, topk_i, topk_w);
  k_hist<<<16, 256, 0, stream>>>(topk_i, topk_w, counts, loadw);
  k_offsets<<<1, 256, 0, stream>>>(counts, loadw, po, tile_e, (float*)d_out);
  k_bucket<<<16, 256, 0, stream>>>(topk_i, topk_w, po, cursor, btok, bw);
  k_gemm1<<<dim3(MT_MAX, I_DIM / 128), 256, 0, stream>>>(xb, wgT, wuT, btok, tile_e, hbuf);
  k_gemm2<<<dim3(MT_MAX, H_DIM / 128), 256, 0, stream>>>(hbuf, wdT, btok, bw, tile_e, yout);
}

// Round 2
// 575.937 us; speedup vs baseline: 1.2079x; 1.2079x over previous
//
#include <hip/hip_runtime.h>

// ---------------- problem constants ----------------
#define N_TOK 8192      // B*S tokens
#define H_DIM 1024
#define I_DIM 2048
#define N_EXP 8
#define TOPK  2
#define CAP   17408     // 16384 + 8*128 (per-expert padding to 128)
#define MT_MAX 136      // CAP / 128

// ---------------- workspace layout (bytes) ----------------
#define OFF_TOPK_I 0u          // 16384 i32
#define OFF_TOPK_W 65536u      // 16384 f32 (RAW softmax probs of chosen experts)
#define OFF_COUNTS 131072u     // 8 i32
#define OFF_LOAD   131104u     // 8 f32
#define OFF_CURSOR 131136u     // 8 i32
#define OFF_PO     131168u     // 16 i32
#define OFF_TILE_E 131232u     // 152 i32 (136 used)
#define OFF_BTOK   131840u     // 17408 i32
#define OFF_BW     201472u     // 17408 f32
#define CTRL_BYTES 271104u     // memset covers everything above
#define OFF_TSLOT  271104u     // 16384 i32 (slot of (t,k)) — fully overwritten, no memset
#define OFF_WGT  1048576u                      // 8*2048*1024*2 = 33554432
#define OFF_WUT  (OFF_WGT + 33554432u)
#define OFF_WDT  (OFF_WUT + 33554432u)
#define OFF_HB   (OFF_WDT + 33554432u)         // 17408*2048*2 = 71303168
#define OFF_XB   (OFF_HB + 71303168u)          // 8192*1024*2 = 16777216 (x in bf16)
// obuf (CAP*1024 bf16 = 35.7 MB) reuses WGT+WUT (dead after gemm1)

typedef __attribute__((ext_vector_type(8))) short bf16x8;
typedef __attribute__((ext_vector_type(8))) unsigned short u16x8;
typedef __attribute__((ext_vector_type(4))) unsigned short u16x4;
typedef __attribute__((ext_vector_type(4))) float f32x4;

__device__ __forceinline__ unsigned short f2bf(float f) {
  union { float f; unsigned int u; } v; v.f = f;
  unsigned int r = (v.u + 0x7FFFu + ((v.u >> 16) & 1u)) >> 16;
  return (unsigned short)r;
}
__device__ __forceinline__ float bf2f(unsigned short u) {
  union { unsigned int u; float f; } v; v.u = ((unsigned int)u) << 16;
  return v.f;
}
__device__ __forceinline__ u16x8 pack8(float4 a, float4 b) {
  u16x8 r;
  r[0] = f2bf(a.x); r[1] = f2bf(a.y); r[2] = f2bf(a.z); r[3] = f2bf(a.w);
  r[4] = f2bf(b.x); r[5] = f2bf(b.y); r[6] = f2bf(b.z); r[7] = f2bf(b.w);
  return r;
}
__device__ __forceinline__ f32x4 mfma32(bf16x8 a, bf16x8 b, f32x4 c) {
  return __builtin_amdgcn_mfma_f32_16x16x32_bf16(a, b, c, 0, 0, 0);
}
// async global->LDS, 16B per lane; lds dest must be wave-uniform base (HW adds lane*16)
__device__ __forceinline__ void gll16(const void* g, void* l) {
  __builtin_amdgcn_global_load_lds(
      (const __attribute__((address_space(1))) unsigned int*)g,
      (__attribute__((address_space(3))) unsigned int*)l, 16, 0, 0);
}

// ---------------- K1: x f32 -> bf16 (once; GEMM1 A-operand becomes lds-DMA-able) ----------------
__global__ __launch_bounds__(256) void k_xcast(const float* __restrict__ x,
                                               unsigned short* __restrict__ xb)
{
  int idx = blockIdx.x * 256 + threadIdx.x;          // 8 floats each
  const float4* s = (const float4*)x + (size_t)idx * 2;
  float4 a = s[0], b = s[1];
  *(u16x8*)&xb[(size_t)idx * 8] = pack8(a, b);
}

// ---------------- K2: tiled transpose f32 -> bf16 of the 3 weight tensors ----------------
__global__ __launch_bounds__(256) void k_transpose(
    const float* __restrict__ wg, const float* __restrict__ wu, const float* __restrict__ wd,
    unsigned short* __restrict__ wgT, unsigned short* __restrict__ wuT,
    unsigned short* __restrict__ wdT)
{
  __shared__ unsigned short lds[64][65];
  int bid = blockIdx.x;
  int m = bid / 4096; int rem = bid % 4096;
  const float* src; unsigned short* dst; int R, C;
  if (m == 0)      { src = wg; dst = wgT; R = 1024; C = 2048; }
  else if (m == 1) { src = wu; dst = wuT; R = 1024; C = 2048; }
  else             { src = wd; dst = wdT; R = 2048; C = 1024; }
  int e = rem / 512; int trem = rem % 512;
  int tcc = C / 64;
  int r0 = (trem / tcc) * 64, c0 = (trem % tcc) * 64;
  size_t ebase = (size_t)e * R * C;
  dst += ebase;
  int tid = threadIdx.x;
  int lr = tid >> 3;            // 0..31
  int lc = (tid & 7) * 8;       // 0..56
#pragma unroll
  for (int p = 0; p < 2; ++p) {
    int row = p * 32 + lr;
    size_t off = ebase + (size_t)(r0 + row) * C + c0 + lc;
    float4 q0 = *(const float4*)&src[off];
    float4 q1 = *(const float4*)&src[off + 4];
    unsigned short tmp[8]; *(u16x8*)tmp = pack8(q0, q1);
#pragma unroll
    for (int j = 0; j < 8; ++j) lds[row][lc + j] = tmp[j];
  }
  __syncthreads();
#pragma unroll
  for (int p = 0; p < 2; ++p) {
    int drow = p * 32 + lr;     // local c index
    unsigned short tmp[8];
#pragma unroll
    for (int j = 0; j < 8; ++j) tmp[j] = lds[lc + j][drow];
    *(u16x8*)&dst[(size_t)(c0 + drow) * R + r0 + lc] = *(const u16x8*)tmp;
  }
}

// ---------------- K3: router (1 wave per token, NO global atomics) ----------------
__global__ __launch_bounds__(256) void k_router(
    const float* __restrict__ x, const float* __restrict__ gw,
    int* __restrict__ topk_i, float* __restrict__ topk_w)
{
  int wave = threadIdx.x >> 6, lane = threadIdx.x & 63;
  int t = blockIdx.x * 4 + wave;
  const float* xr = x + (size_t)t * H_DIM;
  float acc[8];
#pragma unroll
  for (int e = 0; e < 8; ++e) acc[e] = 0.f;
#pragma unroll
  for (int it = 0; it < H_DIM / 64; ++it) {
    int h = it * 64 + lane;
    float xv = xr[h];
    float4 g0 = *(const float4*)&gw[h * 8];
    float4 g1 = *(const float4*)&gw[h * 8 + 4];
    acc[0] += xv * g0.x; acc[1] += xv * g0.y; acc[2] += xv * g0.z; acc[3] += xv * g0.w;
    acc[4] += xv * g1.x; acc[5] += xv * g1.y; acc[6] += xv * g1.z; acc[7] += xv * g1.w;
  }
#pragma unroll
  for (int off = 32; off > 0; off >>= 1) {
#pragma unroll
    for (int e = 0; e < 8; ++e) acc[e] += __shfl_xor(acc[e], off);
  }
  if (lane == 0) {
    float m = acc[0];
#pragma unroll
    for (int e = 1; e < 8; ++e) m = fmaxf(m, acc[e]);
    float p[8], s = 0.f;
#pragma unroll
    for (int e = 0; e < 8; ++e) { p[e] = __expf(acc[e] - m); s += p[e]; }
    float inv = 1.f / s;
#pragma unroll
    for (int e = 0; e < 8; ++e) p[e] *= inv;
    int i1 = 0;
#pragma unroll
    for (int e = 1; e < 8; ++e) if (p[e] > p[i1]) i1 = e;   // strict > = lowest-index ties
    int i2 = (i1 == 0) ? 1 : 0;
#pragma unroll
    for (int e = 0; e < 8; ++e) if (e != i1 && p[e] > p[i2]) i2 = e;
    topk_i[t * 2]     = i1; topk_i[t * 2 + 1] = i2;
    topk_w[t * 2]     = p[i1]; topk_w[t * 2 + 1] = p[i2];   // RAW probs
  }
}

// ---------------- K3b: histogram (counts + load) via LDS, few global atomics ----------------
__global__ __launch_bounds__(256) void k_hist(
    const int* __restrict__ topk_i, const float* __restrict__ topk_w,
    int* __restrict__ counts, float* __restrict__ loadw)
{
  __shared__ int c[8]; __shared__ float l[8];
  int tid = threadIdx.x;
  if (tid < 8) { c[tid] = 0; l[tid] = 0.f; }
  __syncthreads();
  int base = blockIdx.x * 1024 + tid * 4;   // 16 blocks cover 16384 entries
#pragma unroll
  for (int j = 0; j < 4; ++j) {
    int e = topk_i[base + j];
    float w = topk_w[base + j];
    atomicAdd(&c[e], 1);
    atomicAdd(&l[e], w);
  }
  __syncthreads();
  if (tid < 8) { atomicAdd(&counts[tid], c[tid]); atomicAdd(&loadw[tid], l[tid]); }
}

// ---------------- K4: padded offsets + tile->expert map + aux loss ----------------
__global__ __launch_bounds__(256) void k_offsets(
    const int* __restrict__ counts, const float* __restrict__ loadw,
    int* __restrict__ po, int* __restrict__ tile_e, float* __restrict__ out)
{
  __shared__ int spo[9];
  if (threadIdx.x == 0) {
    int a = 0;
    for (int e = 0; e < 8; ++e) { spo[e] = a; po[e] = a; a += (counts[e] + 127) & ~127; }
    spo[8] = a; po[8] = a;
    float s = 0.f;
    for (int e = 0; e < 8; ++e) s += loadw[e] * (float)counts[e];
    out[(size_t)N_TOK * H_DIM] =
        s * ((float)N_EXP * 1e-3f) / ((float)N_TOK * (float)N_TOK * (float)TOPK);
  }
  __syncthreads();
  int mt = threadIdx.x;
  if (mt < MT_MAX) {
    int te = -1, beg = mt * 128;
    if (beg < spo[8]) {
      for (int e = 0; e < 8; ++e) if (beg >= spo[e] && beg < spo[e + 1]) te = e;
    }
    tile_e[mt] = te;
  }
}

// ---------------- K5: bucket fill — LDS local ranks, 8 global atomics/block ----------------
__global__ __launch_bounds__(256) void k_bucket(
    const int* __restrict__ topk_i, const float* __restrict__ topk_w,
    const int* __restrict__ po, int* __restrict__ cursor,
    int* __restrict__ btok, float* __restrict__ bw, int* __restrict__ tslot)
{
  __shared__ int c[8];
  __shared__ int basee[8];
  int tid = threadIdx.x;
  if (tid < 8) c[tid] = 0;
  __syncthreads();
  int base = blockIdx.x * 1024 + tid * 4;   // 16 blocks cover 16384 entries
  int e4[4], r4[4]; float w4[4];
#pragma unroll
  for (int j = 0; j < 4; ++j) {
    int idx = base + j;
    int e = topk_i[idx];
    e4[j] = e;
    r4[j] = atomicAdd(&c[e], 1);            // LDS atomic: local rank
    int t = idx >> 1;
    float p0 = topk_w[t * 2], p1 = topk_w[t * 2 + 1];
    w4[j] = topk_w[idx] / (p0 + p1);        // renormalized weight
  }
  __syncthreads();
  if (tid < 8) basee[tid] = po[tid] + atomicAdd(&cursor[tid], c[tid]);
  __syncthreads();
#pragma unroll
  for (int j = 0; j < 4; ++j) {
    int idx = base + j;
    int slot = basee[e4[j]] + r4[j];
    btok[slot] = idx >> 1;
    bw[slot] = w4[j];
    tslot[idx] = slot;                       // inverse map for gather-combine
  }
}

// ---------------- K6: grouped GEMM1 (global_load_lds staging), gate+up+SiLU -> hbuf ----------------
// grid: x = nt (16)  [XCD i gets nt ≡ i mod 8 → B working set ~8MB/XCD], y = mt (136)
__global__ __launch_bounds__(256, 2) void k_gemm1(
    const unsigned short* __restrict__ xb,
    const unsigned short* __restrict__ wgT, const unsigned short* __restrict__ wuT,
    const int* __restrict__ btok, const int* __restrict__ tile_e,
    unsigned short* __restrict__ hbuf)
{
  int mt = blockIdx.y, nt = blockIdx.x;
  int e = tile_e[mt];
  if (e < 0) return;
  __shared__ unsigned short As[128 * 32];
  __shared__ unsigned short Bg[128 * 32];
  __shared__ unsigned short Bu[128 * 32];
  int tid = threadIdx.x;
  int wave = tid >> 6, lane = tid & 63;
  int wm = wave >> 1, wn = wave & 1;
  int quad = lane >> 4, l16 = lane & 15;

  // staging geometry: per 1KB wave-chunk, lane -> row = base + (lane>>2), k-chunk = (lane&3)*8
  int srow = lane >> 2;            // 0..15
  int sko  = (lane & 3) * 8;      // elem offset in K
  int ar0 = wave * 16 + srow;      // rows 0..63
  int ar1 = 64 + wave * 16 + srow; // rows 64..127
  int t0 = btok[mt * 128 + ar0];   // pad slots are 0 (memset) -> safe
  int t1 = btok[mt * 128 + ar1];
  const unsigned short* ga0 = xb + (size_t)t0 * H_DIM + sko;
  const unsigned short* ga1 = xb + (size_t)t1 * H_DIM + sko;
  const unsigned short* bgb = wgT + ((size_t)e * I_DIM + nt * 128) * H_DIM;
  const unsigned short* bub = wuT + ((size_t)e * I_DIM + nt * 128) * H_DIM;
  const unsigned short* gg0 = bgb + (size_t)ar0 * H_DIM + sko;
  const unsigned short* gg1 = bgb + (size_t)ar1 * H_DIM + sko;
  const unsigned short* gu0 = bub + (size_t)ar0 * H_DIM + sko;
  const unsigned short* gu1 = bub + (size_t)ar1 * H_DIM + sko;
  unsigned lb0 = (unsigned)(wave * 16) * 32;        // wave-uniform LDS elem base
  unsigned lb1 = (unsigned)(64 + wave * 16) * 32;

  f32x4 accG[4][4], accU[4][4];
  f32x4 z = {0.f, 0.f, 0.f, 0.f};
#pragma unroll
  for (int i = 0; i < 4; ++i)
#pragma unroll
    for (int j = 0; j < 4; ++j) { accG[i][j] = z; accU[i][j] = z; }

  for (int k0 = 0; k0 < H_DIM; k0 += 32) {
    gll16(ga0 + k0, &As[lb0]);
    gll16(ga1 + k0, &As[lb1]);
    gll16(gg0 + k0, &Bg[lb0]);
    gll16(gg1 + k0, &Bg[lb1]);
    gll16(gu0 + k0, &Bu[lb0]);
    gll16(gu1 + k0, &Bu[lb1]);
    __syncthreads();                                 // drains vmcnt -> LDS tiles ready
    bf16x8 af[4];
#pragma unroll
    for (int i = 0; i < 4; ++i)
      af[i] = *(const bf16x8*)&As[(wm * 64 + i * 16 + l16) * 32 + quad * 8];
#pragma unroll
    for (int j = 0; j < 4; ++j) {
      bf16x8 vg = *(const bf16x8*)&Bg[(wn * 64 + j * 16 + l16) * 32 + quad * 8];
      bf16x8 vu = *(const bf16x8*)&Bu[(wn * 64 + j * 16 + l16) * 32 + quad * 8];
#pragma unroll
      for (int i = 0; i < 4; ++i) {
        accG[i][j] = mfma32(af[i], vg, accG[i][j]);
        accU[i][j] = mfma32(af[i], vu, accU[i][j]);
      }
    }
    __syncthreads();
  }
#pragma unroll
  for (int i = 0; i < 4; ++i) {
#pragma unroll
    for (int r = 0; r < 4; ++r) {
      int row = mt * 128 + wm * 64 + i * 16 + quad * 4 + r;
      size_t base = (size_t)row * I_DIM + nt * 128 + wn * 64 + l16;
#pragma unroll
      for (int j = 0; j < 4; ++j) {
        float g = accG[i][j][r], u = accU[i][j][r];
        float sg = g / (1.f + __expf(-g));    // SiLU
        hbuf[base + j * 16] = f2bf(sg * u);
      }
    }
  }
}

// ---------------- K7: grouped GEMM2 (global_load_lds staging), plain bf16 stores -> obuf ----------------
// grid: x = nt (8)  [XCD i gets exactly nt=i → B working set = 4MB/XCD, fits L2], y = mt (136)
__global__ __launch_bounds__(256, 2) void k_gemm2(
    const unsigned short* __restrict__ hbuf, const unsigned short* __restrict__ wdT,
    const int* __restrict__ tile_e, unsigned short* __restrict__ obuf)
{
  int mt = blockIdx.y, nt = blockIdx.x;
  int e = tile_e[mt];
  if (e < 0) return;
  __shared__ unsigned short As[128 * 32];
  __shared__ unsigned short Bs[128 * 32];
  int tid = threadIdx.x;
  int wave = tid >> 6, lane = tid & 63;
  int wm = wave >> 1, wn = wave & 1;
  int quad = lane >> 4, l16 = lane & 15;

  int srow = lane >> 2;
  int sko  = (lane & 3) * 8;
  int ar0 = wave * 16 + srow;
  int ar1 = 64 + wave * 16 + srow;
  const unsigned short* ga0 = hbuf + (size_t)(mt * 128 + ar0) * I_DIM + sko;
  const unsigned short* ga1 = hbuf + (size_t)(mt * 128 + ar1) * I_DIM + sko;
  const unsigned short* bb = wdT + ((size_t)e * H_DIM + nt * 128) * I_DIM;
  const unsigned short* gb0 = bb + (size_t)ar0 * I_DIM + sko;
  const unsigned short* gb1 = bb + (size_t)ar1 * I_DIM + sko;
  unsigned lb0 = (unsigned)(wave * 16) * 32;
  unsigned lb1 = (unsigned)(64 + wave * 16) * 32;

  f32x4 acc[4][4];
  f32x4 z = {0.f, 0.f, 0.f, 0.f};
#pragma unroll
  for (int i = 0; i < 4; ++i)
#pragma unroll
    for (int j = 0; j < 4; ++j) acc[i][j] = z;

  for (int k0 = 0; k0 < I_DIM; k0 += 32) {
    gll16(ga0 + k0, &As[lb0]);
    gll16(ga1 + k0, &As[lb1]);
    gll16(gb0 + k0, &Bs[lb0]);
    gll16(gb1 + k0, &Bs[lb1]);
    __syncthreads();
    bf16x8 af[4];
#pragma unroll
    for (int i = 0; i < 4; ++i)
      af[i] = *(const bf16x8*)&As[(wm * 64 + i * 16 + l16) * 32 + quad * 8];
#pragma unroll
    for (int j = 0; j < 4; ++j) {
      bf16x8 vb = *(const bf16x8*)&Bs[(wn * 64 + j * 16 + l16) * 32 + quad * 8];
#pragma unroll
      for (int i = 0; i < 4; ++i) acc[i][j] = mfma32(af[i], vb, acc[i][j]);
    }
    __syncthreads();
  }
#pragma unroll
  for (int i = 0; i < 4; ++i) {
#pragma unroll
    for (int r = 0; r < 4; ++r) {
      int s = mt * 128 + wm * 64 + i * 16 + quad * 4 + r;
      size_t base = (size_t)s * H_DIM + nt * 128 + wn * 64 + l16;
#pragma unroll
      for (int j = 0; j < 4; ++j)
        obuf[base + j * 16] = f2bf(acc[i][j][r]);
    }
  }
}

// ---------------- K8: gather-combine y[t] = w0*obuf[s0] + w1*obuf[s1] ----------------
__global__ __launch_bounds__(256) void k_final(
    const unsigned short* __restrict__ obuf, const int* __restrict__ tslot,
    const float* __restrict__ bw, float* __restrict__ y)
{
  int t = blockIdx.x;
  int s0 = tslot[t * 2], s1 = tslot[t * 2 + 1];
  float w0 = bw[s0], w1 = bw[s1];
  int c = threadIdx.x * 4;
  u16x4 o0 = *(const u16x4*)&obuf[(size_t)s0 * H_DIM + c];
  u16x4 o1 = *(const u16x4*)&obuf[(size_t)s1 * H_DIM + c];
  float4 r;
  r.x = w0 * bf2f(o0[0]) + w1 * bf2f(o1[0]);
  r.y = w0 * bf2f(o0[1]) + w1 * bf2f(o1[1]);
  r.z = w0 * bf2f(o0[2]) + w1 * bf2f(o1[2]);
  r.w = w0 * bf2f(o0[3]) + w1 * bf2f(o1[3]);
  *(float4*)&y[(size_t)t * H_DIM + c] = r;
}

extern "C" void kernel_launch(void* const* d_in, const int* in_sizes, int n_in,
                              void* d_out, int out_size, void* d_ws, size_t ws_size,
                              hipStream_t stream)
{
  (void)in_sizes; (void)n_in; (void)out_size; (void)ws_size;
  const float* x  = (const float*)d_in[0];
  const float* gw = (const float*)d_in[1];
  const float* wg = (const float*)d_in[2];
  const float* wu = (const float*)d_in[3];
  const float* wd = (const float*)d_in[4];
  char* ws = (char*)d_ws;

  int*   topk_i = (int*)  (ws + OFF_TOPK_I);
  float* topk_w = (float*)(ws + OFF_TOPK_W);
  int*   counts = (int*)  (ws + OFF_COUNTS);
  float* loadw  = (float*)(ws + OFF_LOAD);
  int*   cursor = (int*)  (ws + OFF_CURSOR);
  int*   po     = (int*)  (ws + OFF_PO);
  int*   tile_e = (int*)  (ws + OFF_TILE_E);
  int*   btok   = (int*)  (ws + OFF_BTOK);
  float* bw     = (float*)(ws + OFF_BW);
  int*   tslot  = (int*)  (ws + OFF_TSLOT);
  unsigned short* wgT  = (unsigned short*)(ws + OFF_WGT);
  unsigned short* wuT  = (unsigned short*)(ws + OFF_WUT);
  unsigned short* wdT  = (unsigned short*)(ws + OFF_WDT);
  unsigned short* hbuf = (unsigned short*)(ws + OFF_HB);
  unsigned short* xb   = (unsigned short*)(ws + OFF_XB);
  unsigned short* obuf = (unsigned short*)(ws + OFF_WGT);  // reuse wgT+wuT (dead after gemm1)
  float* yout = (float*)d_out;

  (void)hipMemsetAsync(ws, 0, CTRL_BYTES, stream);
  k_xcast<<<(N_TOK * H_DIM) / 2048, 256, 0, stream>>>(x, xb);
  k_transpose<<<12288, 256, 0, stream>>>(wg, wu, wd, wgT, wuT, wdT);
  k_router<<<N_TOK / 4, 256, 0, stream>>>(x, gw, topk_i, topk_w);
  k_hist<<<16, 256, 0, stream>>>(topk_i, topk_w, counts, loadw);
  k_offsets<<<1, 256, 0, stream>>>(counts, loadw, po, tile_e, (float*)d_out);
  k_bucket<<<16, 256, 0, stream>>>(topk_i, topk_w, po, cursor, btok, bw, tslot);
  k_gemm1<<<dim3(I_DIM / 128, MT_MAX), 256, 0, stream>>>(xb, wgT, wuT, btok, tile_e, hbuf);
  k_gemm2<<<dim3(H_DIM / 128, MT_MAX), 256, 0, stream>>>(hbuf, wdT, tile_e, obuf);
  k_final<<<N_TOK, 256, 0, stream>>>(obuf, tslot, bw, yout);
}

// Round 3
// 560.975 us; speedup vs baseline: 1.2401x; 1.0267x over previous
//
#include <hip/hip_runtime.h>

// ---------------- problem constants ----------------
#define N_TOK 8192      // B*S tokens
#define H_DIM 1024
#define I_DIM 2048
#define N_EXP 8
#define TOPK  2
#define CAP   18432     // 16384 + 8*256 (per-expert padding to 256)
#define MT_MAX 72       // CAP / 256

// ---------------- workspace layout (bytes) ----------------
#define OFF_TOPK_I 0u          // 16384 i32
#define OFF_TOPK_W 65536u      // 16384 f32 (RAW softmax probs of chosen experts)
#define OFF_COUNTS 131072u     // 8 i32
#define OFF_LOAD   131104u     // 8 f32
#define OFF_CURSOR 131136u     // 8 i32
#define OFF_PO     131168u     // 16 i32
#define OFF_TILE_E 131232u     // 128 i32 (72 used)
#define OFF_BTOK   131744u     // 18432 i32
#define OFF_BW     205472u     // 18432 f32
#define CTRL_BYTES 279200u     // memset covers everything above
#define OFF_TSLOT  279552u     // 16384 i32 — fully overwritten, no memset
#define OFF_WGT  1048576u                      // 8*2048*1024*2 = 33554432
#define OFF_WUT  (OFF_WGT + 33554432u)
#define OFF_WDT  (OFF_WUT + 33554432u)
#define OFF_HB   (OFF_WDT + 33554432u)         // 18432*2048*2 = 75497472
#define OFF_XB   (OFF_HB + 75497472u)          // 8192*1024*2 = 16777216 (x in bf16)
// obuf (18432*1024 bf16 = 37.7 MB) reuses WGT+WUT (dead after gemm1)

typedef __attribute__((ext_vector_type(8))) short bf16x8;
typedef __attribute__((ext_vector_type(8))) unsigned short u16x8;
typedef __attribute__((ext_vector_type(4))) unsigned short u16x4;
typedef __attribute__((ext_vector_type(4))) float f32x4;

#define BAR() __builtin_amdgcn_s_barrier()
#define PRIO1() __builtin_amdgcn_s_setprio(1)
#define PRIO0() __builtin_amdgcn_s_setprio(0)
#define WAITV0() asm volatile("s_waitcnt vmcnt(0)" ::: "memory")
#define WAITV6() asm volatile("s_waitcnt vmcnt(6)" ::: "memory")

__device__ __forceinline__ unsigned short f2bf(float f) {
  union { float f; unsigned int u; } v; v.f = f;
  unsigned int r = (v.u + 0x7FFFu + ((v.u >> 16) & 1u)) >> 16;
  return (unsigned short)r;
}
__device__ __forceinline__ float bf2f(unsigned short u) {
  union { unsigned int u; float f; } v; v.u = ((unsigned int)u) << 16;
  return v.f;
}
__device__ __forceinline__ u16x8 pack8(float4 a, float4 b) {
  u16x8 r;
  r[0] = f2bf(a.x); r[1] = f2bf(a.y); r[2] = f2bf(a.z); r[3] = f2bf(a.w);
  r[4] = f2bf(b.x); r[5] = f2bf(b.y); r[6] = f2bf(b.z); r[7] = f2bf(b.w);
  return r;
}
__device__ __forceinline__ f32x4 mfma32(bf16x8 a, bf16x8 b, f32x4 c) {
  return __builtin_amdgcn_mfma_f32_16x16x32_bf16(a, b, c, 0, 0, 0);
}
// async global->LDS, 16B per lane; lds dest must be wave-uniform base (HW adds lane*16)
__device__ __forceinline__ void gll16(const void* g, void* l) {
  __builtin_amdgcn_global_load_lds(
      (const __attribute__((address_space(1))) unsigned int*)g,
      (__attribute__((address_space(3))) unsigned int*)l, 16, 0, 0);
}

// ---------------- K1: x f32 -> bf16 ----------------
__global__ __launch_bounds__(256) void k_xcast(const float* __restrict__ x,
                                               unsigned short* __restrict__ xb)
{
  int idx = blockIdx.x * 256 + threadIdx.x;          // 8 floats each
  const float4* s = (const float4*)x + (size_t)idx * 2;
  float4 a = s[0], b = s[1];
  *(u16x8*)&xb[(size_t)idx * 8] = pack8(a, b);
}

// ---------------- K2: tiled transpose f32 -> bf16 of the 3 weight tensors ----------------
__global__ __launch_bounds__(256) void k_transpose(
    const float* __restrict__ wg, const float* __restrict__ wu, const float* __restrict__ wd,
    unsigned short* __restrict__ wgT, unsigned short* __restrict__ wuT,
    unsigned short* __restrict__ wdT)
{
  __shared__ unsigned short lds[64][65];
  int bid = blockIdx.x;
  int m = bid / 4096; int rem = bid % 4096;
  const float* src; unsigned short* dst; int R, C;
  if (m == 0)      { src = wg; dst = wgT; R = 1024; C = 2048; }
  else if (m == 1) { src = wu; dst = wuT; R = 1024; C = 2048; }
  else             { src = wd; dst = wdT; R = 2048; C = 1024; }
  int e = rem / 512; int trem = rem % 512;
  int tcc = C / 64;
  int r0 = (trem / tcc) * 64, c0 = (trem % tcc) * 64;
  size_t ebase = (size_t)e * R * C;
  dst += ebase;
  int tid = threadIdx.x;
  int lr = tid >> 3;            // 0..31
  int lc = (tid & 7) * 8;       // 0..56
#pragma unroll
  for (int p = 0; p < 2; ++p) {
    int row = p * 32 + lr;
    size_t off = ebase + (size_t)(r0 + row) * C + c0 + lc;
    float4 q0 = *(const float4*)&src[off];
    float4 q1 = *(const float4*)&src[off + 4];
    unsigned short tmp[8]; *(u16x8*)tmp = pack8(q0, q1);
#pragma unroll
    for (int j = 0; j < 8; ++j) lds[row][lc + j] = tmp[j];
  }
  __syncthreads();
#pragma unroll
  for (int p = 0; p < 2; ++p) {
    int drow = p * 32 + lr;     // local c index
    unsigned short tmp[8];
#pragma unroll
    for (int j = 0; j < 8; ++j) tmp[j] = lds[lc + j][drow];
    *(u16x8*)&dst[(size_t)(c0 + drow) * R + r0 + lc] = *(const u16x8*)tmp;
  }
}

// ---------------- K3: router (1 wave per token) ----------------
__global__ __launch_bounds__(256) void k_router(
    const float* __restrict__ x, const float* __restrict__ gw,
    int* __restrict__ topk_i, float* __restrict__ topk_w)
{
  int wave = threadIdx.x >> 6, lane = threadIdx.x & 63;
  int t = blockIdx.x * 4 + wave;
  const float* xr = x + (size_t)t * H_DIM;
  float acc[8];
#pragma unroll
  for (int e = 0; e < 8; ++e) acc[e] = 0.f;
#pragma unroll
  for (int it = 0; it < H_DIM / 64; ++it) {
    int h = it * 64 + lane;
    float xv = xr[h];
    float4 g0 = *(const float4*)&gw[h * 8];
    float4 g1 = *(const float4*)&gw[h * 8 + 4];
    acc[0] += xv * g0.x; acc[1] += xv * g0.y; acc[2] += xv * g0.z; acc[3] += xv * g0.w;
    acc[4] += xv * g1.x; acc[5] += xv * g1.y; acc[6] += xv * g1.z; acc[7] += xv * g1.w;
  }
#pragma unroll
  for (int off = 32; off > 0; off >>= 1) {
#pragma unroll
    for (int e = 0; e < 8; ++e) acc[e] += __shfl_xor(acc[e], off);
  }
  if (lane == 0) {
    float m = acc[0];
#pragma unroll
    for (int e = 1; e < 8; ++e) m = fmaxf(m, acc[e]);
    float p[8], s = 0.f;
#pragma unroll
    for (int e = 0; e < 8; ++e) { p[e] = __expf(acc[e] - m); s += p[e]; }
    float inv = 1.f / s;
#pragma unroll
    for (int e = 0; e < 8; ++e) p[e] *= inv;
    int i1 = 0;
#pragma unroll
    for (int e = 1; e < 8; ++e) if (p[e] > p[i1]) i1 = e;   // strict > = lowest-index ties
    int i2 = (i1 == 0) ? 1 : 0;
#pragma unroll
    for (int e = 0; e < 8; ++e) if (e != i1 && p[e] > p[i2]) i2 = e;
    topk_i[t * 2]     = i1; topk_i[t * 2 + 1] = i2;
    topk_w[t * 2]     = p[i1]; topk_w[t * 2 + 1] = p[i2];   // RAW probs
  }
}

// ---------------- K3b: histogram ----------------
__global__ __launch_bounds__(256) void k_hist(
    const int* __restrict__ topk_i, const float* __restrict__ topk_w,
    int* __restrict__ counts, float* __restrict__ loadw)
{
  __shared__ int c[8]; __shared__ float l[8];
  int tid = threadIdx.x;
  if (tid < 8) { c[tid] = 0; l[tid] = 0.f; }
  __syncthreads();
  int base = blockIdx.x * 1024 + tid * 4;
#pragma unroll
  for (int j = 0; j < 4; ++j) {
    int e = topk_i[base + j];
    float w = topk_w[base + j];
    atomicAdd(&c[e], 1);
    atomicAdd(&l[e], w);
  }
  __syncthreads();
  if (tid < 8) { atomicAdd(&counts[tid], c[tid]); atomicAdd(&loadw[tid], l[tid]); }
}

// ---------------- K4: padded offsets (256) + tile->expert map + aux loss ----------------
__global__ __launch_bounds__(256) void k_offsets(
    const int* __restrict__ counts, const float* __restrict__ loadw,
    int* __restrict__ po, int* __restrict__ tile_e, float* __restrict__ out)
{
  __shared__ int spo[9];
  if (threadIdx.x == 0) {
    int a = 0;
    for (int e = 0; e < 8; ++e) { spo[e] = a; po[e] = a; a += (counts[e] + 255) & ~255; }
    spo[8] = a; po[8] = a;
    float s = 0.f;
    for (int e = 0; e < 8; ++e) s += loadw[e] * (float)counts[e];
    out[(size_t)N_TOK * H_DIM] =
        s * ((float)N_EXP * 1e-3f) / ((float)N_TOK * (float)N_TOK * (float)TOPK);
  }
  __syncthreads();
  int mt = threadIdx.x;
  if (mt < MT_MAX) {
    int te = -1, beg = mt * 256;
    if (beg < spo[8]) {
      for (int e = 0; e < 8; ++e) if (beg >= spo[e] && beg < spo[e + 1]) te = e;
    }
    tile_e[mt] = te;
  }
}

// ---------------- K5: bucket fill ----------------
__global__ __launch_bounds__(256) void k_bucket(
    const int* __restrict__ topk_i, const float* __restrict__ topk_w,
    const int* __restrict__ po, int* __restrict__ cursor,
    int* __restrict__ btok, float* __restrict__ bw, int* __restrict__ tslot)
{
  __shared__ int c[8];
  __shared__ int basee[8];
  int tid = threadIdx.x;
  if (tid < 8) c[tid] = 0;
  __syncthreads();
  int base = blockIdx.x * 1024 + tid * 4;
  int e4[4], r4[4]; float w4[4];
#pragma unroll
  for (int j = 0; j < 4; ++j) {
    int idx = base + j;
    int e = topk_i[idx];
    e4[j] = e;
    r4[j] = atomicAdd(&c[e], 1);
    int t = idx >> 1;
    float p0 = topk_w[t * 2], p1 = topk_w[t * 2 + 1];
    w4[j] = topk_w[idx] / (p0 + p1);
  }
  __syncthreads();
  if (tid < 8) basee[tid] = po[tid] + atomicAdd(&cursor[tid], c[tid]);
  __syncthreads();
#pragma unroll
  for (int j = 0; j < 4; ++j) {
    int idx = base + j;
    int slot = basee[e4[j]] + r4[j];
    btok[slot] = idx >> 1;
    bw[slot] = w4[j];
    tslot[idx] = slot;
  }
}

// ---------------- K6: GEMM1 256x128 dual-B, BK=64, 4-phase pipelined, swizzled LDS ----------------
// grid: x = nt (16), y = mt (72); 512 threads = 8 waves (4M x 2N); 128KB LDS (2 buffers)
__global__ __launch_bounds__(512, 2) void k_gemm1(
    const unsigned short* __restrict__ xb,
    const unsigned short* __restrict__ wgT, const unsigned short* __restrict__ wuT,
    const int* __restrict__ btok, const int* __restrict__ tile_e,
    unsigned short* __restrict__ hbuf)
{
  int mt = blockIdx.y, nt = blockIdx.x;
  int e = tile_e[mt];
  if (e < 0) return;
  // buffer: A[256][64] @0, Bg[128][64] @16384, Bu[128][64] @24576 (elems); x2 buffers
  __shared__ unsigned short lds[65536];
  int tid = threadIdx.x;
  int wave = tid >> 6, lane = tid & 63;
  int wm = wave >> 1, wn = wave & 1;      // 4M x 2N
  int quad = lane >> 4, l16 = lane & 15;

  // ---- staging geometry: wave w stages rows [w*16, w*16+16) of each half (2 calls) ----
  int rp = lane >> 3;                      // 0..7
  int chunk = (lane & 7) ^ rp;             // swizzled 16B slot (rowp&7 == rp)
  const unsigned short* sA[2][2]; const unsigned short* sBg[2]; const unsigned short* sBu[2];
  unsigned dA[2][2], dB[2];
#pragma unroll
  for (int h = 0; h < 2; ++h)
#pragma unroll
    for (int c = 0; c < 2; ++c) {
      int rowp = wave * 16 + c * 8 + rp;
      int tok = btok[mt * 256 + h * 128 + rowp];
      sA[h][c] = xb + (size_t)tok * H_DIM + chunk * 8;
      dA[h][c] = (unsigned)(h * 128 + wave * 16 + c * 8) * 64;
    }
#pragma unroll
  for (int c = 0; c < 2; ++c) {
    int rowp = wave * 16 + c * 8 + rp;
    sBg[c] = wgT + ((size_t)e * I_DIM + nt * 128 + rowp) * H_DIM + chunk * 8;
    sBu[c] = wuT + ((size_t)e * I_DIM + nt * 128 + rowp) * H_DIM + chunk * 8;
    dB[c] = (unsigned)(wave * 16 + c * 8) * 64;
  }

  f32x4 accG[4][4], accU[4][4];
  f32x4 z = {0.f, 0.f, 0.f, 0.f};
#pragma unroll
  for (int i = 0; i < 4; ++i)
#pragma unroll
    for (int j = 0; j < 4; ++j) { accG[i][j] = z; accU[i][j] = z; }

  // swizzled frag readers
  int fsw = l16 & 7;
  // prologue: stage tile 0 into buffer 0
#pragma unroll
  for (int h = 0; h < 2; ++h)
#pragma unroll
    for (int c = 0; c < 2; ++c) gll16(sA[h][c], &lds[dA[h][c]]);
#pragma unroll
  for (int c = 0; c < 2; ++c) { gll16(sBg[c], &lds[16384 + dB[c]]); gll16(sBu[c], &lds[24576 + dB[c]]); }
  WAITV0();
  BAR();

  for (int t = 0; t < 16; ++t) {
    unsigned bo = (unsigned)(t & 1) * 32768;
    unsigned bo1 = bo ^ 32768;
    int kel = (t + 1) * 64;
    bool pf = (t < 15);
    // ---- P0: read A frags + Bg(nf0,1); stage A(t+1); MFMA G nf0-1 ----
    bf16x8 a[4][2];
#pragma unroll
    for (int m = 0; m < 4; ++m)
#pragma unroll
      for (int ks = 0; ks < 2; ++ks) {
        int row = wm * 64 + m * 16 + l16;
        a[m][ks] = *(const bf16x8*)&lds[bo + row * 64 + (((ks * 4 + quad) ^ fsw) * 8)];
      }
    bf16x8 bg[2][2];
#pragma unroll
    for (int nf = 0; nf < 2; ++nf)
#pragma unroll
      for (int ks = 0; ks < 2; ++ks) {
        int col = wn * 64 + nf * 16 + l16;
        bg[nf][ks] = *(const bf16x8*)&lds[bo + 16384 + col * 64 + (((ks * 4 + quad) ^ fsw) * 8)];
      }
    if (pf) {
#pragma unroll
      for (int h = 0; h < 2; ++h)
#pragma unroll
        for (int c = 0; c < 2; ++c) gll16(sA[h][c] + kel, &lds[bo1 + dA[h][c]]);
    }
    BAR();
    PRIO1();
#pragma unroll
    for (int nf = 0; nf < 2; ++nf)
#pragma unroll
      for (int m = 0; m < 4; ++m)
#pragma unroll
        for (int ks = 0; ks < 2; ++ks) accG[m][nf] = mfma32(a[m][ks], bg[nf][ks], accG[m][nf]);
    PRIO0();
    BAR();
    // ---- P1: read Bg(nf2,3); stage Bg+Bu(t+1); MFMA G nf2-3 ----
#pragma unroll
    for (int nf = 0; nf < 2; ++nf)
#pragma unroll
      for (int ks = 0; ks < 2; ++ks) {
        int col = wn * 64 + (2 + nf) * 16 + l16;
        bg[nf][ks] = *(const bf16x8*)&lds[bo + 16384 + col * 64 + (((ks * 4 + quad) ^ fsw) * 8)];
      }
    if (pf) {
#pragma unroll
      for (int c = 0; c < 2; ++c) { gll16(sBg[c] + kel, &lds[bo1 + 16384 + dB[c]]); gll16(sBu[c] + kel, &lds[bo1 + 24576 + dB[c]]); }
    }
    BAR();
    PRIO1();
#pragma unroll
    for (int nf = 0; nf < 2; ++nf)
#pragma unroll
      for (int m = 0; m < 4; ++m)
#pragma unroll
        for (int ks = 0; ks < 2; ++ks) accG[m][2 + nf] = mfma32(a[m][ks], bg[nf][ks], accG[m][2 + nf]);
    PRIO0();
    BAR();
    // ---- P2: read Bu(nf0,1); MFMA U nf0-1 ----
#pragma unroll
    for (int nf = 0; nf < 2; ++nf)
#pragma unroll
      for (int ks = 0; ks < 2; ++ks) {
        int col = wn * 64 + nf * 16 + l16;
        bg[nf][ks] = *(const bf16x8*)&lds[bo + 24576 + col * 64 + (((ks * 4 + quad) ^ fsw) * 8)];
      }
    BAR();
    PRIO1();
#pragma unroll
    for (int nf = 0; nf < 2; ++nf)
#pragma unroll
      for (int m = 0; m < 4; ++m)
#pragma unroll
        for (int ks = 0; ks < 2; ++ks) accU[m][nf] = mfma32(a[m][ks], bg[nf][ks], accU[m][nf]);
    PRIO0();
    BAR();
    // ---- P3: read Bu(nf2,3); MFMA U nf2-3; boundary drain ----
#pragma unroll
    for (int nf = 0; nf < 2; ++nf)
#pragma unroll
      for (int ks = 0; ks < 2; ++ks) {
        int col = wn * 64 + (2 + nf) * 16 + l16;
        bg[nf][ks] = *(const bf16x8*)&lds[bo + 24576 + col * 64 + (((ks * 4 + quad) ^ fsw) * 8)];
      }
    BAR();
    PRIO1();
#pragma unroll
    for (int nf = 0; nf < 2; ++nf)
#pragma unroll
      for (int m = 0; m < 4; ++m)
#pragma unroll
        for (int ks = 0; ks < 2; ++ks) accU[m][2 + nf] = mfma32(a[m][ks], bg[nf][ks], accU[m][2 + nf]);
    PRIO0();
    WAITV0();      // youngest prefetch is ~2 phases old -> near-free
    BAR();
  }
  // epilogue: SiLU(g)*u -> hbuf
#pragma unroll
  for (int m = 0; m < 4; ++m)
#pragma unroll
    for (int r = 0; r < 4; ++r) {
      int row = mt * 256 + wm * 64 + m * 16 + quad * 4 + r;
      size_t base = (size_t)row * I_DIM + nt * 128 + wn * 64 + l16;
#pragma unroll
      for (int nf = 0; nf < 4; ++nf) {
        float g = accG[m][nf][r], u = accU[m][nf][r];
        float sg = g / (1.f + __expf(-g));
        hbuf[base + nf * 16] = f2bf(sg * u);
      }
    }
}

// ---------------- K7: GEMM2 256x128, BK=64, 3-buffer counted-vmcnt pipeline ----------------
// grid: x = nt (8), y = mt (72); 512 threads = 8 waves (2M x 4N); 144KB LDS (3 buffers)
__global__ __launch_bounds__(512, 2) void k_gemm2(
    const unsigned short* __restrict__ hbuf, const unsigned short* __restrict__ wdT,
    const int* __restrict__ tile_e, unsigned short* __restrict__ obuf)
{
  int mt = blockIdx.y, nt = blockIdx.x;
  int e = tile_e[mt];
  if (e < 0) return;
  // buffer: A[256][64] @0, B[128][64] @16384 (elems), 24576 elems/buffer, x3
  __shared__ unsigned short lds[73728];
  int tid = threadIdx.x;
  int wave = tid >> 6, lane = tid & 63;
  int wm = wave >> 2, wn = wave & 3;      // 2M x 4N
  int quad = lane >> 4, l16 = lane & 15;

  int rp = lane >> 3;
  int chunk = (lane & 7) ^ rp;
  const unsigned short* sA[2][2]; const unsigned short* sB[2];
  unsigned dA[2][2], dB[2];
#pragma unroll
  for (int h = 0; h < 2; ++h)
#pragma unroll
    for (int c = 0; c < 2; ++c) {
      int rowp = wave * 16 + c * 8 + rp;
      sA[h][c] = hbuf + (size_t)(mt * 256 + h * 128 + rowp) * I_DIM + chunk * 8;
      dA[h][c] = (unsigned)(h * 128 + wave * 16 + c * 8) * 64;
    }
#pragma unroll
  for (int c = 0; c < 2; ++c) {
    int rowp = wave * 16 + c * 8 + rp;
    sB[c] = wdT + ((size_t)e * H_DIM + nt * 128 + rowp) * I_DIM + chunk * 8;
    dB[c] = (unsigned)(wave * 16 + c * 8) * 64;
  }

  f32x4 acc[8][2];
  f32x4 z = {0.f, 0.f, 0.f, 0.f};
#pragma unroll
  for (int i = 0; i < 8; ++i) { acc[i][0] = z; acc[i][1] = z; }

  int fsw = l16 & 7;
  // prologue: stage tiles 0,1 into buffers 0,1 (6 ops each); wait oldest 6
#pragma unroll
  for (int tt = 0; tt < 2; ++tt) {
    unsigned bo = (unsigned)tt * 24576;
    int kel = tt * 64;
#pragma unroll
    for (int h = 0; h < 2; ++h)
#pragma unroll
      for (int c = 0; c < 2; ++c) gll16(sA[h][c] + kel, &lds[bo + dA[h][c]]);
#pragma unroll
    for (int c = 0; c < 2; ++c) gll16(sB[c] + kel, &lds[bo + 16384 + dB[c]]);
  }
  WAITV6();
  BAR();

  unsigned boA = 0, boB = 24576, boC = 49152;   // read, next, stage-target(t+2)
  for (int t = 0; t < 32; ++t) {
    int kel = (t + 2) * 64;
    bool pf = (t < 30);
    bf16x8 b[2][2];
#pragma unroll
    for (int nf = 0; nf < 2; ++nf)
#pragma unroll
      for (int ks = 0; ks < 2; ++ks) {
        int col = wn * 32 + nf * 16 + l16;
        b[nf][ks] = *(const bf16x8*)&lds[boA + 16384 + col * 64 + (((ks * 4 + quad) ^ fsw) * 8)];
      }
    // ---- P0: A mfr0-3 + MFMA ----
    {
      bf16x8 a[4][2];
#pragma unroll
      for (int m = 0; m < 4; ++m)
#pragma unroll
        for (int ks = 0; ks < 2; ++ks) {
          int row = wm * 128 + m * 16 + l16;
          a[m][ks] = *(const bf16x8*)&lds[boA + row * 64 + (((ks * 4 + quad) ^ fsw) * 8)];
        }
      if (pf) {
#pragma unroll
        for (int h = 0; h < 2; ++h)
#pragma unroll
          for (int c = 0; c < 2; ++c) gll16(sA[h][c] + kel, &lds[boC + dA[h][c]]);
      }
      BAR();
      PRIO1();
#pragma unroll
      for (int m = 0; m < 4; ++m)
#pragma unroll
        for (int nf = 0; nf < 2; ++nf)
#pragma unroll
          for (int ks = 0; ks < 2; ++ks) acc[m][nf] = mfma32(a[m][ks], b[nf][ks], acc[m][nf]);
      PRIO0();
      BAR();
    }
    // ---- P1: A mfr4-7 + MFMA; boundary counted wait ----
    {
      bf16x8 a[4][2];
#pragma unroll
      for (int m = 0; m < 4; ++m)
#pragma unroll
        for (int ks = 0; ks < 2; ++ks) {
          int row = wm * 128 + (4 + m) * 16 + l16;
          a[m][ks] = *(const bf16x8*)&lds[boA + row * 64 + (((ks * 4 + quad) ^ fsw) * 8)];
        }
      if (pf) {
#pragma unroll
        for (int c = 0; c < 2; ++c) gll16(sB[c] + kel, &lds[boC + 16384 + dB[c]]);
      }
      BAR();
      PRIO1();
#pragma unroll
      for (int m = 0; m < 4; ++m)
#pragma unroll
        for (int nf = 0; nf < 2; ++nf)
#pragma unroll
          for (int ks = 0; ks < 2; ++ks) acc[4 + m][nf] = mfma32(a[m][ks], b[nf][ks], acc[4 + m][nf]);
      PRIO0();
    }
    if (pf) { WAITV6(); } else { WAITV0(); }   // never drain to 0 in steady state
    BAR();
    unsigned tmp = boA; boA = boB; boB = boC; boC = tmp;
  }
  // epilogue: bf16 store to obuf
#pragma unroll
  for (int m = 0; m < 8; ++m)
#pragma unroll
    for (int r = 0; r < 4; ++r) {
      int s = mt * 256 + wm * 128 + m * 16 + quad * 4 + r;
      size_t base = (size_t)s * H_DIM + nt * 128 + wn * 32 + l16;
      obuf[base]      = f2bf(acc[m][0][r]);
      obuf[base + 16] = f2bf(acc[m][1][r]);
    }
}

// ---------------- K8: gather-combine y[t] = w0*obuf[s0] + w1*obuf[s1] ----------------
__global__ __launch_bounds__(256) void k_final(
    const unsigned short* __restrict__ obuf, const int* __restrict__ tslot,
    const float* __restrict__ bw, float* __restrict__ y)
{
  int t = blockIdx.x;
  int s0 = tslot[t * 2], s1 = tslot[t * 2 + 1];
  float w0 = bw[s0], w1 = bw[s1];
  int c = threadIdx.x * 4;
  u16x4 o0 = *(const u16x4*)&obuf[(size_t)s0 * H_DIM + c];
  u16x4 o1 = *(const u16x4*)&obuf[(size_t)s1 * H_DIM + c];
  float4 r;
  r.x = w0 * bf2f(o0[0]) + w1 * bf2f(o1[0]);
  r.y = w0 * bf2f(o0[1]) + w1 * bf2f(o1[1]);
  r.z = w0 * bf2f(o0[2]) + w1 * bf2f(o1[2]);
  r.w = w0 * bf2f(o0[3]) + w1 * bf2f(o1[3]);
  *(float4*)&y[(size_t)t * H_DIM + c] = r;
}

extern "C" void kernel_launch(void* const* d_in, const int* in_sizes, int n_in,
                              void* d_out, int out_size, void* d_ws, size_t ws_size,
                              hipStream_t stream)
{
  (void)in_sizes; (void)n_in; (void)out_size; (void)ws_size;
  const float* x  = (const float*)d_in[0];
  const float* gw = (const float*)d_in[1];
  const float* wg = (const float*)d_in[2];
  const float* wu = (const float*)d_in[3];
  const float* wd = (const float*)d_in[4];
  char* ws = (char*)d_ws;

  int*   topk_i = (int*)  (ws + OFF_TOPK_I);
  float* topk_w = (float*)(ws + OFF_TOPK_W);
  int*   counts = (int*)  (ws + OFF_COUNTS);
  float* loadw  = (float*)(ws + OFF_LOAD);
  int*   cursor = (int*)  (ws + OFF_CURSOR);
  int*   po     = (int*)  (ws + OFF_PO);
  int*   tile_e = (int*)  (ws + OFF_TILE_E);
  int*   btok   = (int*)  (ws + OFF_BTOK);
  float* bw     = (float*)(ws + OFF_BW);
  int*   tslot  = (int*)  (ws + OFF_TSLOT);
  unsigned short* wgT  = (unsigned short*)(ws + OFF_WGT);
  unsigned short* wuT  = (unsigned short*)(ws + OFF_WUT);
  unsigned short* wdT  = (unsigned short*)(ws + OFF_WDT);
  unsigned short* hbuf = (unsigned short*)(ws + OFF_HB);
  unsigned short* xb   = (unsigned short*)(ws + OFF_XB);
  unsigned short* obuf = (unsigned short*)(ws + OFF_WGT);  // reuse wgT+wuT (dead after gemm1)
  float* yout = (float*)d_out;

  (void)hipMemsetAsync(ws, 0, CTRL_BYTES, stream);
  k_xcast<<<(N_TOK * H_DIM) / 2048, 256, 0, stream>>>(x, xb);
  k_transpose<<<12288, 256, 0, stream>>>(wg, wu, wd, wgT, wuT, wdT);
  k_router<<<N_TOK / 4, 256, 0, stream>>>(x, gw, topk_i, topk_w);
  k_hist<<<16, 256, 0, stream>>>(topk_i, topk_w, counts, loadw);
  k_offsets<<<1, 256, 0, stream>>>(counts, loadw, po, tile_e, (float*)d_out);
  k_bucket<<<16, 256, 0, stream>>>(topk_i, topk_w, po, cursor, btok, bw, tslot);
  k_gemm1<<<dim3(I_DIM / 128, MT_MAX), 512, 0, stream>>>(xb, wgT, wuT, btok, tile_e, hbuf);
  k_gemm2<<<dim3(H_DIM / 128, MT_MAX), 512, 0, stream>>>(hbuf, wdT, tile_e, obuf);
  k_final<<<N_TOK, 256, 0, stream>>>(obuf, tslot, bw, yout);
}